// Round 6
// baseline (194.656 us; speedup 1.0000x reference)
//
#include <hip/hip_runtime.h>
#include <math.h>

#define NUM_CLASSES 80
#define C_CH (NUM_CLASSES + 1)
#define MAX_T 128   // dedup LDS capacity per wave (T=64 here)

__device__ __forceinline__ float softplusf(float x) {
    return fmaxf(x, 0.f) + log1pf(expf(-fabsf(x)));
}
__device__ __forceinline__ float sigmoidf_(float x) {
    return 1.f / (1.f + expf(-x));
}

// d_ws layout (4-byte words):
//   [0]      done-counter (uint)  -- zeroed by a 64-byte memset each call
//   [1..15]  pad
//   [16..)   bgpart[nbg]          per-block plane sums of softplus(ch0)
//            tpart[4*nTblk]       SoA {lb, lo, lc, n} per target-block
//            osp[2B], ocnt[2B]    per-(image,scale) occupied softplus sum / count
// Partial slots are written unconditionally by their owning block: no zeroing.
// Identity: bce_bg = plane_sum(softplus(ch0)) - occupied_sum; bg_cnt = B*HW - occ_cnt.

__global__ void __launch_bounds__(256) mono_kernel(
    const float* __restrict__ cls_p4, const float* __restrict__ reg_p4,
    const float* __restrict__ cls_p5, const float* __restrict__ reg_p5,
    const int* __restrict__ t4_cls, const float* __restrict__ t4_box, const float* __restrict__ t4_mask,
    const int* __restrict__ t5_cls, const float* __restrict__ t5_box, const float* __restrict__ t5_mask,
    unsigned int* __restrict__ counter,
    float* __restrict__ bgpart, float* __restrict__ tpart,
    float* __restrict__ osp_arr, float* __restrict__ ocnt_arr,
    int B, int T, int nbg4, int nbg5, int nTblk, int nblk_total,
    float* __restrict__ out)
{
    const int tid  = threadIdx.x;
    const int wave = tid >> 6;
    const int lane = tid & 63;
    const int blk  = (int)blockIdx.x;
    const int nbg  = nbg4 + nbg5;
    const int BT   = B * T;

    __shared__ float s4[4][4];
    __shared__ unsigned int cells[4][MAX_T];
    __shared__ int lastflag;

    if (blk < nbg) {
        // ---------- role 1: background plane sum of softplus(channel 0), 256 cells/block ----------
        float sp = 0.f;
        if (blk < nbg4) {
            int b = blk / 25, j = blk - b * 25;          // 6400/256 = 25 blocks/image
            int cell = j * 256 + tid;
            sp = softplusf(cls_p4[(size_t)b * (C_CH * 6400) + cell]);
        } else {
            int o = blk - nbg4;
            int b = o / 7, j = o - b * 7;                // ceil(1600/256) = 7 blocks/image
            int cell = j * 256 + tid;
            if (cell < 1600)
                sp = softplusf(cls_p5[(size_t)b * (C_CH * 1600) + cell]);
        }
        for (int off = 32; off > 0; off >>= 1) sp += __shfl_down(sp, off, 64);
        if (lane == 0) s4[wave][0] = sp;
        __syncthreads();
        if (tid == 0) bgpart[blk] = s4[0][0] + s4[1][0] + s4[2][0] + s4[3][0];
    } else if (blk < nbg + nTblk) {
        // ---------- role 2: per-target losses, 1 target per wave, 4 per block ----------
        const int tg = (blk - nbg) * 4 + wave;
        float lb = 0.f, lo = 0.f, lcv = 0.f, msum = 0.f;

        if (tg < 2 * BT) {
            const int scale = (tg >= BT) ? 1 : 0;
            const int ti = scale ? tg - BT : tg;
            const int b = ti / T;

            const float* cls_p = scale ? cls_p5 : cls_p4;
            const float* reg_p = scale ? reg_p5 : reg_p4;
            const int*   tc    = scale ? t5_cls : t4_cls;
            const float* tb_   = scale ? t5_box : t4_box;
            const float* tm    = scale ? t5_mask : t4_mask;
            const int W  = scale ? 40 : 80;
            const int HW = W * W;

            const float mask = tm[ti];
            const int   cid  = tc[ti];
            const float tx = tb_[ti * 4 + 0] * (float)W;
            const float ty = tb_[ti * 4 + 1] * (float)W;
            const float tw = tb_[ti * 4 + 2] * (float)W;
            const float th = tb_[ti * 4 + 3] * (float)W;
            const int gx = (int)fminf(fmaxf(tx, 0.f), (float)(W - 1));
            const int gy = (int)fminf(fmaxf(ty, 0.f), (float)(W - 1));
            const int cell = gy * W + gx;

            const float* cvbase = cls_p + (size_t)b * C_CH * HW + cell;

            // issue ALL scattered loads before any use (one latency round)
            float x0 = cvbase[(size_t)(lane + 1) * HW];                     // class c = lane
            float x1 = (lane < NUM_CLASSES - 64)
                         ? cvbase[(size_t)(lane + 65) * HW] : 0.f;          // class c = lane+64
            float rvq  = (lane < 4) ? reg_p[(size_t)(b * 4 + lane) * HW + cell] : 0.f;
            float objq = (lane == 0) ? cvbase[0] : 0.f;

            float fsum = 0.f;
            {
                float x = x0;
                float tgt = (lane == cid) ? 1.f : 0.f;
                float bce = softplusf(x) - x * tgt;
                float p = sigmoidf_(x);
                float pt = p * tgt + (1.f - p) * (1.f - tgt);
                float om = 1.f - pt;
                fsum += 0.25f * om * om * bce;                              // lane<80 always true (64<80)
            }
            if (lane < NUM_CLASSES - 64) {
                float x = x1;
                float tgt = (lane + 64 == cid) ? 1.f : 0.f;
                float bce = softplusf(x) - x * tgt;
                float p = sigmoidf_(x);
                float pt = p * tgt + (1.f - p) * (1.f - tgt);
                float om = 1.f - pt;
                fsum += 0.25f * om * om * bce;
            }
            for (int off = 32; off > 0; off >>= 1) fsum += __shfl_down(fsum, off, 64);

            float rv0 = __shfl(rvq, 0, 64), rv1 = __shfl(rvq, 1, 64);
            float rv2 = __shfl(rvq, 2, 64), rv3 = __shfl(rvq, 3, 64);

            if (lane == 0) {
                lcv = (fsum * (1.f / (float)NUM_CLASSES)) * mask;
                lo  = softplusf(-objq) * mask;

                float dx = sigmoidf_(rv0), dy = sigmoidf_(rv1);
                float dw = expf(fminf(fmaxf(rv2, -4.f), 4.f));
                float dh = expf(fminf(fmaxf(rv3, -4.f), 4.f));
                float px = (float)gx + dx, py = (float)gy + dy;
                float d, a, s = 0.f;
                d = (px - dw * 0.5f) - (tx - tw * 0.5f); a = fabsf(d); s += (a < 1.f) ? 0.5f * d * d : a - 0.5f;
                d = (py - dh * 0.5f) - (ty - th * 0.5f); a = fabsf(d); s += (a < 1.f) ? 0.5f * d * d : a - 0.5f;
                d = (px + dw * 0.5f) - (tx + tw * 0.5f); a = fabsf(d); s += (a < 1.f) ? 0.5f * d * d : a - 0.5f;
                d = (py + dh * 0.5f) - (ty + th * 0.5f); a = fabsf(d); s += (a < 1.f) ? 0.5f * d * d : a - 0.5f;
                lb = (s * 0.25f) * mask;
                msum = mask;
            }
        }

        if (lane == 0) { s4[wave][0] = lb; s4[wave][1] = lo; s4[wave][2] = lcv; s4[wave][3] = msum; }
        __syncthreads();
        if (tid == 0) {
            const int tb = blk - nbg;
            #pragma unroll
            for (int q = 0; q < 4; q++)
                tpart[q * nTblk + tb] = s4[0][q] + s4[1][q] + s4[2][q] + s4[3][q];
        }
    } else {
        // ---------- role 3: per-(image,scale) occupied-cell dedup + obj gather, 1 pair/wave ----------
        const int pbase = (blk - nbg - nTblk) * 4;
        const int p = pbase + wave;
        float osp = 0.f, ocnt = 0.f;
        const bool valid_pair = (p < 2 * B) && (T <= MAX_T);
        int scale = 0, b = 0, W = 80, HW = 6400;
        if (valid_pair) {
            scale = p / B; b = p - scale * B;
            const float* tb_ = scale ? t5_box : t4_box;
            const float* tm  = scale ? t5_mask : t4_mask;
            W = scale ? 40 : 80; HW = W * W;
            for (int i = lane; i < T; i += 64) {
                const int ti = b * T + i;
                unsigned int cellv = 0xFFFFFFFFu;
                if (tm[ti] > 0.f) {
                    const float txx = tb_[ti * 4 + 0] * (float)W;
                    const float tyy = tb_[ti * 4 + 1] * (float)W;
                    const int gxx = (int)fminf(fmaxf(txx, 0.f), (float)(W - 1));
                    const int gyy = (int)fminf(fmaxf(tyy, 0.f), (float)(W - 1));
                    cellv = (unsigned)(gyy * W + gxx);
                }
                cells[wave][i] = cellv;
            }
        }
        __syncthreads();
        if (valid_pair) {
            const float* cls_p = scale ? cls_p5 : cls_p4;
            for (int i = lane; i < T; i += 64) {
                unsigned int cv = cells[wave][i];
                if (cv != 0xFFFFFFFFu) {
                    bool first = true;
                    for (int j = 0; j < i; j++)
                        if (cells[wave][j] == cv) { first = false; break; }
                    if (first) {
                        osp  += softplusf(cls_p[(size_t)b * C_CH * HW + (int)cv]);
                        ocnt += 1.f;
                    }
                }
            }
        }
        for (int off = 32; off > 0; off >>= 1) {
            osp  += __shfl_down(osp,  off, 64);
            ocnt += __shfl_down(ocnt, off, 64);
        }
        if (lane == 0) { s4[wave][0] = osp; s4[wave][1] = ocnt; }
        __syncthreads();
        if (tid == 0) {
            #pragma unroll
            for (int w = 0; w < 4; w++) {
                int pp = pbase + w;
                if (pp < 2 * B) {
                    osp_arr[pp]  = s4[w][0];
                    ocnt_arr[pp] = s4[w][1];
                }
            }
        }
    }

    // ---------- completion: last finishing block performs the final reduction ----------
    if (tid == 0) {
        __threadfence();                                   // release this block's partial writes
        unsigned int old = atomicAdd(counter, 1u);
        lastflag = (old == (unsigned int)(nblk_total - 1)) ? 1 : 0;
    }
    __syncthreads();
    if (lastflag) {
        __threadfence();                                   // acquire all blocks' partials

        float lb = 0.f, lo = 0.f, lc = 0.f, n = 0.f;
        float bg4 = 0.f, bg5 = 0.f, o4 = 0.f, c4 = 0.f, o5 = 0.f, c5 = 0.f;
        for (int i = tid; i < nTblk; i += 256) {
            lb += tpart[i];
            lo += tpart[nTblk + i];
            lc += tpart[2 * nTblk + i];
            n  += tpart[3 * nTblk + i];
        }
        for (int i = tid; i < nbg4; i += 256) bg4 += bgpart[i];
        for (int i = tid; i < nbg5; i += 256) bg5 += bgpart[nbg4 + i];
        for (int p = tid; p < B; p += 256) { o4 += osp_arr[p];     c4 += ocnt_arr[p]; }
        for (int p = tid; p < B; p += 256) { o5 += osp_arr[B + p]; c5 += ocnt_arr[B + p]; }

        __shared__ float red[4][10];
        float vals[10] = { lb, lo, lc, n, bg4, bg5, o4, c4, o5, c5 };
        #pragma unroll
        for (int k = 0; k < 10; k++) {
            float v = vals[k];
            for (int off = 32; off > 0; off >>= 1) v += __shfl_down(v, off, 64);
            vals[k] = v;
        }
        if (lane == 0) {
            #pragma unroll
            for (int k = 0; k < 10; k++) red[wave][k] = vals[k];
        }
        __syncthreads();
        if (tid == 0) {
            float t[10];
            #pragma unroll
            for (int k = 0; k < 10; k++)
                t[k] = red[0][k] + red[1][k] + red[2][k] + red[3][k];

            float lbt = t[0], lot = t[1], lct = t[2], nt = t[3];
            float bce_bg4 = t[4] - t[6];
            float bce_bg5 = t[5] - t[8];
            float cnt4 = (float)(B * 6400) - t[7];
            float cnt5 = (float)(B * 1600) - t[9];
            lot += 0.05f * ((cnt4 > 0.f) ? bce_bg4 / fmaxf(cnt4, 1.f) : 0.f);
            lot += 0.05f * ((cnt5 > 0.f) ? bce_bg5 / fmaxf(cnt5, 1.f) : 0.f);
            float nd = fmaxf(nt, 1.f);
            if (nt > 0.f) { lbt /= nd; lct /= nd; }
            lot /= fmaxf(nt, 1.f);
            out[0] = 2.0f * lbt + 1.0f * lot + 0.5f * lct;
        }
    }
}

extern "C" void kernel_launch(void* const* d_in, const int* in_sizes, int n_in,
                              void* d_out, int out_size, void* d_ws, size_t ws_size,
                              hipStream_t stream) {
    const float* cls_p4 = (const float*)d_in[0];
    const float* reg_p4 = (const float*)d_in[1];
    const float* cls_p5 = (const float*)d_in[2];
    const float* reg_p5 = (const float*)d_in[3];
    const int*   t4_cls = (const int*)d_in[4];
    const float* t4_box = (const float*)d_in[5];
    const float* t4_mask= (const float*)d_in[6];
    const int*   t5_cls = (const int*)d_in[7];
    const float* t5_box = (const float*)d_in[8];
    const float* t5_mask= (const float*)d_in[9];

    const int B = in_sizes[0] / (C_CH * 6400);   // cls_p4: B x 81 x 80 x 80
    const int T = in_sizes[4] / B;               // t4_cls: B x T
    const int BT = B * T;

    const int nbg4  = B * 25;                    // 256 cells per block
    const int nbg5  = B * 7;
    const int nbg   = nbg4 + nbg5;
    const int nTblk = (2 * BT + 3) / 4;          // 4 targets per block, 1 per wave
    const int ndblk = (2 * B + 3) / 4;           // 4 (image,scale) pairs per block
    const int nblk_total = nbg + nTblk + ndblk;

    unsigned int* counter = (unsigned int*)d_ws; // word 0
    float* bgpart  = (float*)d_ws + 16;
    float* tpart   = bgpart + nbg;
    float* osp_arr = tpart + (size_t)4 * nTblk;
    float* ocnt_arr= osp_arr + 2 * B;

    hipMemsetAsync(d_ws, 0, 64, stream);         // zero the done-counter

    mono_kernel<<<nblk_total, 256, 0, stream>>>(
        cls_p4, reg_p4, cls_p5, reg_p5,
        t4_cls, t4_box, t4_mask, t5_cls, t5_box, t5_mask,
        counter, bgpart, tpart, osp_arr, ocnt_arr,
        B, T, nbg4, nbg5, nTblk, nblk_total, (float*)d_out);
}

// Round 7
// 129.802 us; speedup vs baseline: 1.4996x; 1.4996x over previous
//
#include <hip/hip_runtime.h>
#include <math.h>

#define NUM_CLASSES 80
#define C_CH (NUM_CLASSES + 1)

__device__ __forceinline__ float softplusf(float x) {
    return fmaxf(x, 0.f) + log1pf(expf(-fabsf(x)));
}
__device__ __forceinline__ float sigmoidf_(float x) {
    return 1.f / (1.f + expf(-x));
}

// ws layout (4-byte words):
//   flags4  : (B*6400+31)/32 words   bit-packed occupancy (p4)  -- memset to 0 each call
//   flags5  : (B*1600+31)/32 words   (p5)
//   tpart   : nTblk*4 floats   {lb,lo,lc,n} per target-block    -- written unconditionally
//   bgpart4 : nb4*2 floats     {softplus_sum, count} per bg-block (p4)
//   bgpart5 : nb5*2 floats     (p5)
// Pipeline: memset(33KB) -> target (sets flags) -> bg (reads flags) -> final (reduce).
// NO device-scope fences anywhere: kernel boundaries are the coherence points
// (R6 measured per-block __threadfence at ~+55us total — never again).

__global__ void __launch_bounds__(256) target_kernel(
    const float* __restrict__ cls_p4, const float* __restrict__ reg_p4,
    const float* __restrict__ cls_p5, const float* __restrict__ reg_p5,
    const int* __restrict__ t4_cls, const float* __restrict__ t4_box, const float* __restrict__ t4_mask,
    const int* __restrict__ t5_cls, const float* __restrict__ t5_box, const float* __restrict__ t5_mask,
    float* __restrict__ tpart, unsigned int* __restrict__ flags4, unsigned int* __restrict__ flags5,
    int B, int T)
{
    const int BT = B * T;
    const int wave = threadIdx.x >> 6;
    const int lane = threadIdx.x & 63;
    const int tg = blockIdx.x * 4 + wave;      // 1 target per wave, 4 per block

    float lb = 0.f, lo = 0.f, lcv = 0.f, msum = 0.f;

    if (tg < 2 * BT) {
        const int scale = (tg >= BT) ? 1 : 0;
        const int ti = scale ? tg - BT : tg;
        const int b = ti / T;

        const float* cls_p = scale ? cls_p5 : cls_p4;
        const float* reg_p = scale ? reg_p5 : reg_p4;
        const int*   tc    = scale ? t5_cls : t4_cls;
        const float* tb_   = scale ? t5_box : t4_box;
        const float* tm    = scale ? t5_mask : t4_mask;
        unsigned int* flags = scale ? flags5 : flags4;
        const int W  = scale ? 40 : 80;
        const int HW = W * W;

        const float mask = tm[ti];
        const int   cid  = tc[ti];
        const float tx = tb_[ti * 4 + 0] * (float)W;
        const float ty = tb_[ti * 4 + 1] * (float)W;
        const float tw = tb_[ti * 4 + 2] * (float)W;
        const float th = tb_[ti * 4 + 3] * (float)W;
        const int gx = (int)fminf(fmaxf(tx, 0.f), (float)(W - 1));
        const int gy = (int)fminf(fmaxf(ty, 0.f), (float)(W - 1));
        const int cell = gy * W + gx;

        if (lane == 0 && mask > 0.f) {
            int gidx = b * HW + cell;
            atomicOr(&flags[gidx >> 5], 1u << (gidx & 31));
        }

        const float* cvbase = cls_p + (size_t)b * C_CH * HW + cell;

        // issue ALL scattered loads before any use (single latency round)
        float x0 = cvbase[(size_t)(lane + 1) * HW];                        // class c = lane (<80)
        float x1 = (lane < NUM_CLASSES - 64)
                     ? cvbase[(size_t)(lane + 65) * HW] : 0.f;             // class c = lane+64
        float rvq  = (lane < 4) ? reg_p[(size_t)(b * 4 + lane) * HW + cell] : 0.f;
        float objq = (lane == 0) ? cvbase[0] : 0.f;

        float fsum;
        {
            float x = x0;
            float tgt = (lane == cid) ? 1.f : 0.f;
            float bce = softplusf(x) - x * tgt;
            float p = sigmoidf_(x);
            float pt = p * tgt + (1.f - p) * (1.f - tgt);
            float om = 1.f - pt;
            fsum = 0.25f * om * om * bce;
        }
        if (lane < NUM_CLASSES - 64) {
            float x = x1;
            float tgt = (lane + 64 == cid) ? 1.f : 0.f;
            float bce = softplusf(x) - x * tgt;
            float p = sigmoidf_(x);
            float pt = p * tgt + (1.f - p) * (1.f - tgt);
            float om = 1.f - pt;
            fsum += 0.25f * om * om * bce;
        }
        for (int off = 32; off > 0; off >>= 1) fsum += __shfl_down(fsum, off, 64);

        float rv0 = __shfl(rvq, 0, 64), rv1 = __shfl(rvq, 1, 64);
        float rv2 = __shfl(rvq, 2, 64), rv3 = __shfl(rvq, 3, 64);

        if (lane == 0) {
            lcv = (fsum * (1.f / (float)NUM_CLASSES)) * mask;
            lo  = softplusf(-objq) * mask;

            float dx = sigmoidf_(rv0), dy = sigmoidf_(rv1);
            float dw = expf(fminf(fmaxf(rv2, -4.f), 4.f));
            float dh = expf(fminf(fmaxf(rv3, -4.f), 4.f));
            float px = (float)gx + dx, py = (float)gy + dy;
            float d, a, s = 0.f;
            d = (px - dw * 0.5f) - (tx - tw * 0.5f); a = fabsf(d); s += (a < 1.f) ? 0.5f * d * d : a - 0.5f;
            d = (py - dh * 0.5f) - (ty - th * 0.5f); a = fabsf(d); s += (a < 1.f) ? 0.5f * d * d : a - 0.5f;
            d = (px + dw * 0.5f) - (tx + tw * 0.5f); a = fabsf(d); s += (a < 1.f) ? 0.5f * d * d : a - 0.5f;
            d = (py + dh * 0.5f) - (ty + th * 0.5f); a = fabsf(d); s += (a < 1.f) ? 0.5f * d * d : a - 0.5f;
            lb = (s * 0.25f) * mask;
            msum = mask;
        }
    }

    __shared__ float s4[4][4];
    if (lane == 0) { s4[wave][0] = lb; s4[wave][1] = lo; s4[wave][2] = lcv; s4[wave][3] = msum; }
    __syncthreads();
    if (threadIdx.x < 4) {
        float v = s4[0][threadIdx.x] + s4[1][threadIdx.x] + s4[2][threadIdx.x] + s4[3][threadIdx.x];
        tpart[blockIdx.x * 4 + threadIdx.x] = v;
    }
}

__global__ void __launch_bounds__(256) bg_kernel(
    const float* __restrict__ cls_p4, const float* __restrict__ cls_p5,
    const unsigned int* __restrict__ flags4, const unsigned int* __restrict__ flags5,
    float* __restrict__ bgpart4, float* __restrict__ bgpart5, int nb4)
{
    const int blk = blockIdx.x;
    const int tid = threadIdx.x;
    float sp = 0.f, cnt = 0.f;
    int scale, oblk;
    if (blk < nb4) {
        scale = 0; oblk = blk;
        int b = blk / 25, j = blk - b * 25;       // 6400/256 = 25 blocks per image
        int cell = j * 256 + tid;
        int gidx = b * 6400 + cell;
        unsigned int w = flags4[gidx >> 5];
        if (!((w >> (gidx & 31)) & 1u)) {
            sp = softplusf(cls_p4[(size_t)b * (C_CH * 6400) + cell]);  // channel 0
            cnt = 1.f;
        }
    } else {
        scale = 1; oblk = blk - nb4;
        int b = oblk / 7, j = oblk - b * 7;       // ceil(1600/256) = 7 blocks per image
        int cell = j * 256 + tid;
        if (cell < 1600) {
            int gidx = b * 1600 + cell;
            unsigned int w = flags5[gidx >> 5];
            if (!((w >> (gidx & 31)) & 1u)) {
                sp = softplusf(cls_p5[(size_t)b * (C_CH * 1600) + cell]);
                cnt = 1.f;
            }
        }
    }
    for (int off = 32; off > 0; off >>= 1) {
        sp  += __shfl_down(sp,  off, 64);
        cnt += __shfl_down(cnt, off, 64);
    }
    __shared__ float ss[4][2];
    const int wid = tid >> 6;
    if ((tid & 63) == 0) { ss[wid][0] = sp; ss[wid][1] = cnt; }
    __syncthreads();
    if (tid == 0) {
        float a = ss[0][0] + ss[1][0] + ss[2][0] + ss[3][0];
        float c = ss[0][1] + ss[1][1] + ss[2][1] + ss[3][1];
        float* o = scale ? bgpart5 : bgpart4;
        o[oblk * 2]     = a;
        o[oblk * 2 + 1] = c;
    }
}

__global__ void __launch_bounds__(256) final_kernel(
    const float* __restrict__ tpart, int nTblk,
    const float* __restrict__ bgpart4, int nb4,
    const float* __restrict__ bgpart5, int nb5,
    int B, float* __restrict__ out)
{
    const int tid  = threadIdx.x;
    const int wave = tid >> 6;
    const int lane = tid & 63;

    float lb = 0.f, lo = 0.f, lc = 0.f, n = 0.f, b4 = 0.f, c4 = 0.f, b5 = 0.f, c5 = 0.f;
    for (int i = tid; i < nTblk; i += 256) {
        lb += tpart[i * 4 + 0]; lo += tpart[i * 4 + 1];
        lc += tpart[i * 4 + 2]; n  += tpart[i * 4 + 3];
    }
    for (int i = tid; i < nb4; i += 256) { b4 += bgpart4[2 * i]; c4 += bgpart4[2 * i + 1]; }
    for (int i = tid; i < nb5; i += 256) { b5 += bgpart5[2 * i]; c5 += bgpart5[2 * i + 1]; }

    __shared__ float red[4][8];
    float vals[8] = { lb, lo, lc, n, b4, c4, b5, c5 };
    #pragma unroll
    for (int k = 0; k < 8; k++) {
        float v = vals[k];
        for (int off = 32; off > 0; off >>= 1) v += __shfl_down(v, off, 64);
        vals[k] = v;
    }
    if (lane == 0) {
        #pragma unroll
        for (int k = 0; k < 8; k++) red[wave][k] = vals[k];
    }
    __syncthreads();
    if (tid == 0) {
        float t[8];
        #pragma unroll
        for (int k = 0; k < 8; k++)
            t[k] = red[0][k] + red[1][k] + red[2][k] + red[3][k];

        float lbt = t[0], lot = t[1], lct = t[2], nt = t[3];
        lot += 0.05f * ((t[5] > 0.f) ? t[4] / fmaxf(t[5], 1.f) : 0.f);
        lot += 0.05f * ((t[7] > 0.f) ? t[6] / fmaxf(t[7], 1.f) : 0.f);
        float nd = fmaxf(nt, 1.f);
        if (nt > 0.f) { lbt /= nd; lct /= nd; }
        lot /= fmaxf(nt, 1.f);
        out[0] = 2.0f * lbt + 1.0f * lot + 0.5f * lct;
    }
}

extern "C" void kernel_launch(void* const* d_in, const int* in_sizes, int n_in,
                              void* d_out, int out_size, void* d_ws, size_t ws_size,
                              hipStream_t stream) {
    const float* cls_p4 = (const float*)d_in[0];
    const float* reg_p4 = (const float*)d_in[1];
    const float* cls_p5 = (const float*)d_in[2];
    const float* reg_p5 = (const float*)d_in[3];
    const int*   t4_cls = (const int*)d_in[4];
    const float* t4_box = (const float*)d_in[5];
    const float* t4_mask= (const float*)d_in[6];
    const int*   t5_cls = (const int*)d_in[7];
    const float* t5_box = (const float*)d_in[8];
    const float* t5_mask= (const float*)d_in[9];

    const int B = in_sizes[0] / (C_CH * 6400);   // cls_p4: B x 81 x 80 x 80
    const int T = in_sizes[4] / B;               // t4_cls: B x T
    const int BT = B * T;

    const int fw4 = (B * 6400 + 31) / 32;
    const int fw5 = (B * 1600 + 31) / 32;
    unsigned int* flags4 = (unsigned int*)d_ws;
    unsigned int* flags5 = flags4 + fw4;
    const int nTblk = (2 * BT + 3) / 4;          // 4 targets per block, 1 per wave
    float* tpart   = (float*)(flags5 + fw5);
    const int nb4 = B * 25;
    const int nb5 = B * 7;
    float* bgpart4 = tpart + (size_t)nTblk * 4;
    float* bgpart5 = bgpart4 + (size_t)nb4 * 2;

    hipMemsetAsync(d_ws, 0, (size_t)(fw4 + fw5) * sizeof(unsigned int), stream);

    target_kernel<<<nTblk, 256, 0, stream>>>(
        cls_p4, reg_p4, cls_p5, reg_p5,
        t4_cls, t4_box, t4_mask, t5_cls, t5_box, t5_mask,
        tpart, flags4, flags5, B, T);

    bg_kernel<<<nb4 + nb5, 256, 0, stream>>>(cls_p4, cls_p5, flags4, flags5,
                                             bgpart4, bgpart5, nb4);

    final_kernel<<<1, 256, 0, stream>>>(tpart, nTblk, bgpart4, nb4, bgpart5, nb5,
                                        B, (float*)d_out);
}